// Round 1
// baseline (3200.862 us; speedup 1.0000x reference)
//
#include <hip/hip_runtime.h>

namespace {

constexpr int kB = 64;
constexpr int kL = 4096;
constexpr int kTaps = 32;
constexpr int kNm = 2;
constexpr int kUStep = kTaps * kNm;   // 64 floats per (b,t) slice
constexpr float kLrW = 1.0f / 64.0f;
constexpr float kLrF = 1.0f / 128.0f;
constexpr float kGradMax = 30.0f;
constexpr float kEps = 1e-9f;
constexpr int kPF = 8;                // prefetch depth (steps per chunk)

__device__ __forceinline__ float wsum(float v) {
    // full-wave (64-lane) butterfly sum; every lane ends with the identical total
#pragma unroll
    for (int m = 32; m >= 1; m >>= 1) v += __shfl_xor(v, m, 64);
    return v;
}

__global__ __launch_bounds__(64, 1) void adf_kernel(
    const float* __restrict__ u_r, const float* __restrict__ u_i,
    const float* __restrict__ x_r, const float* __restrict__ x_i,
    const float* __restrict__ w0r_g, const float* __restrict__ w0i_g,
    const float* __restrict__ f0r_g, const float* __restrict__ f0i_g,
    float* __restrict__ out)
{
    const int b = blockIdx.x;
    const int lane = threadIdx.x;     // 0..63
    const int tap = lane >> 1;
    const int j = lane & 1;

    // w[b,i,j,tap] layout: ((b*2+i)*2+j)*32+tap ; i=0 -> wbase, i=1 -> wbase+64
    const int wbase = ((b * kNm + 0) * kNm + j) * kTaps + tap;
    float w0r = w0r_g[wbase];
    float w0i = w0i_g[wbase];
    float w1r = w0r_g[wbase + kNm * kTaps];
    float w1i = w0i_g[wbase + kNm * kTaps];

    float f0r = f0r_g[b * kNm + 0];
    float f0i = f0i_g[b * kNm + 0];
    float f1r = f0r_g[b * kNm + 1];
    float f1i = f0i_g[b * kNm + 1];

    const float* __restrict__ ubr = u_r + (size_t)b * kL * kUStep;
    const float* __restrict__ ubi = u_i + (size_t)b * kL * kUStep;
    const float* __restrict__ xbr = x_r + (size_t)b * kL * kNm;
    const float* __restrict__ xbi = x_i + (size_t)b * kL * kNm;
    float* __restrict__ ob = out + (size_t)b * kL * kNm * 2;

    for (int t0 = 0; t0 < kL; t0 += kPF) {
        float ur[kPF], ui[kPF];
        float d0r[kPF], d0i[kPF], d1r[kPF], d1i[kPF];
#pragma unroll
        for (int s = 0; s < kPF; ++s) {
            const int t = t0 + s;
            ur[s]  = ubr[t * kUStep + lane];
            ui[s]  = ubi[t * kUStep + lane];
            d0r[s] = xbr[t * kNm + 0];
            d0i[s] = xbi[t * kNm + 0];
            d1r[s] = xbr[t * kNm + 1];
            d1i[s] = xbi[t * kNm + 1];
        }
#pragma unroll
        for (int s = 0; s < kPF; ++s) {
            const float a = ur[s], c = ui[s];

            // per-lane partial products for v[i] = sum_l w[i,l] * u[l]
            float p0r = w0r * a - w0i * c;
            float p0i = w0r * c + w0i * a;
            float p1r = w1r * a - w1i * c;
            float p1i = w1r * c + w1i * a;
            float pe  = a * a + c * c;

            const float v0r = wsum(p0r);
            const float v0i = wsum(p0i);
            const float v1r = wsum(p1r);
            const float v1i = wsum(p1i);
            const float uen = wsum(pe) + kEps;

            // k = v * f  (pre-update f) -- this is the step output
            const float k0r = v0r * f0r - v0i * f0i;
            const float k0i = v0r * f0i + v0i * f0r;
            const float k1r = v1r * f1r - v1i * f1i;
            const float k1i = v1r * f1i + v1i * f1r;

            if (lane == 0) {
                *reinterpret_cast<float4*>(ob + (size_t)(t0 + s) * 4) =
                    make_float4(k0r, k0i, k1r, k1i);
            }

            // psi = |f|/f = conj(f)/|f|
            const float af0 = sqrtf(f0r * f0r + f0i * f0i);
            const float af1 = sqrtf(f1r * f1r + f1i * f1i);
            const float ps0r = f0r / af0, ps0i = -f0i / af0;
            const float ps1r = f1r / af1, ps1i = -f1i / af1;

            // e_w = d * psi - v
            const float ew0r = d0r[s] * ps0r - d0i[s] * ps0i - v0r;
            const float ew0i = d0r[s] * ps0i + d0i[s] * ps0r - v0i;
            const float ew1r = d1r[s] * ps1r - d1i[s] * ps1i - v1r;
            const float ew1i = d1r[s] * ps1i + d1i[s] * ps1r - v1i;

            // e_f = d - k
            const float ef0r = d0r[s] - k0r, ef0i = d0i[s] - k0i;
            const float ef1r = d1r[s] - k1r, ef1i = d1i[s] - k1i;

            // gf = -(1/v_energy) * e_f * conj(v)
            const float ven = v0r * v0r + v0i * v0i + v1r * v1r + v1i * v1i + kEps;
            const float nv = -1.0f / ven;
            float gf0r = nv * (ef0r * v0r + ef0i * v0i);
            float gf0i = nv * (ef0i * v0r - ef0r * v0i);
            float gf1r = nv * (ef1r * v1r + ef1i * v1i);
            float gf1i = nv * (ef1i * v1r - ef1r * v1i);

            // clip |gf| at GRAD_MAX (branchless; values identical across lanes)
            const float ag0 = sqrtf(gf0r * gf0r + gf0i * gf0i);
            const float ag1 = sqrtf(gf1r * gf1r + gf1i * gf1i);
            const float sc0 = (ag0 > kGradMax) ? (kGradMax / ag0) : 1.0f;
            const float sc1 = (ag1 > kGradMax) ? (kGradMax / ag1) : 1.0f;
            gf0r *= sc0; gf0i *= sc0;
            gf1r *= sc1; gf1i *= sc1;

            // f -= lr_f * gf
            f0r -= kLrF * gf0r; f0i -= kLrF * gf0i;
            f1r -= kLrF * gf1r; f1i -= kLrF * gf1i;

            // w += (lr_w / u_energy) * e_w * conj(u)   (per-lane element)
            const float su = kLrW / uen;
            const float c0r = su * ew0r, c0i = su * ew0i;
            const float c1r = su * ew1r, c1i = su * ew1i;
            w0r += c0r * a + c0i * c;
            w0i += c0i * a - c0r * c;
            w1r += c1r * a + c1i * c;
            w1i += c1i * a - c1r * c;
        }
    }
}

} // namespace

extern "C" void kernel_launch(void* const* d_in, const int* in_sizes, int n_in,
                              void* d_out, int out_size, void* d_ws, size_t ws_size,
                              hipStream_t stream) {
    const float* u_r  = (const float*)d_in[0];
    const float* u_i  = (const float*)d_in[1];
    const float* x_r  = (const float*)d_in[2];
    const float* x_i  = (const float*)d_in[3];
    const float* w0_r = (const float*)d_in[4];
    const float* w0_i = (const float*)d_in[5];
    const float* f0_r = (const float*)d_in[6];
    const float* f0_i = (const float*)d_in[7];
    float* out = (float*)d_out;

    dim3 grid(kB);
    dim3 block(64);
    adf_kernel<<<grid, block, 0, stream>>>(u_r, u_i, x_r, x_i,
                                           w0_r, w0_i, f0_r, f0_i, out);
}

// Round 2
// 1435.349 us; speedup vs baseline: 2.2300x; 2.2300x over previous
//
#include <hip/hip_runtime.h>

namespace {

constexpr int kB = 64;
constexpr int kL = 4096;
constexpr int kTaps = 32;
constexpr int kNm = 2;
constexpr int kUStep = kTaps * kNm;   // 64 floats per (b,t) slice
constexpr float kLrW = 1.0f / 64.0f;
constexpr float kLrF = 1.0f / 128.0f;
constexpr float kGradMax = 30.0f;
constexpr float kEps = 1e-9f;
constexpr int kPF = 8;                // prefetch depth (steps per chunk)

// Full-wave (64-lane) sum via DPP (VALU pipe, no LDS latency).
// Sequence: row_shr 1/2/4/8 (accumulate within 16-lane rows),
// row_bcast15 (row0->row1, row2->row3), row_bcast31 (lower32->upper32).
// Total lands in lane 63; readlane broadcasts via SGPR.
#define DPP_ADD_F32(v, ctrl)                                                   \
    v += __int_as_float(__builtin_amdgcn_update_dpp(                           \
        0, __float_as_int(v), (ctrl), 0xF, 0xF, true))

__device__ __forceinline__ float wsum(float v) {
    DPP_ADD_F32(v, 0x111);  // row_shr:1
    DPP_ADD_F32(v, 0x112);  // row_shr:2
    DPP_ADD_F32(v, 0x114);  // row_shr:4
    DPP_ADD_F32(v, 0x118);  // row_shr:8
    DPP_ADD_F32(v, 0x142);  // row_bcast:15
    DPP_ADD_F32(v, 0x143);  // row_bcast:31
    return __int_as_float(__builtin_amdgcn_readlane(__float_as_int(v), 63));
}

__device__ __forceinline__ float fast_rcp(float x)  { return __builtin_amdgcn_rcpf(x); }
__device__ __forceinline__ float fast_rsq(float x)  { return __builtin_amdgcn_rsqf(x); }

__global__ __launch_bounds__(64, 1) void adf_kernel(
    const float* __restrict__ u_r, const float* __restrict__ u_i,
    const float* __restrict__ x_r, const float* __restrict__ x_i,
    const float* __restrict__ w0r_g, const float* __restrict__ w0i_g,
    const float* __restrict__ f0r_g, const float* __restrict__ f0i_g,
    float* __restrict__ out)
{
    const int b = blockIdx.x;
    const int lane = threadIdx.x;     // 0..63
    const int tap = lane >> 1;
    const int j = lane & 1;

    // w[b,i,j,tap] layout: ((b*2+i)*2+j)*32+tap ; i=0 -> wbase, i=1 -> wbase+64
    const int wbase = ((b * kNm + 0) * kNm + j) * kTaps + tap;
    float w0r = w0r_g[wbase];
    float w0i = w0i_g[wbase];
    float w1r = w0r_g[wbase + kNm * kTaps];
    float w1i = w0i_g[wbase + kNm * kTaps];

    float f0r = f0r_g[b * kNm + 0];
    float f0i = f0i_g[b * kNm + 0];
    float f1r = f0r_g[b * kNm + 1];
    float f1i = f0i_g[b * kNm + 1];

    const float* __restrict__ ubr = u_r + (size_t)b * kL * kUStep;
    const float* __restrict__ ubi = u_i + (size_t)b * kL * kUStep;
    const float* __restrict__ xbr = x_r + (size_t)b * kL * kNm;
    const float* __restrict__ xbi = x_i + (size_t)b * kL * kNm;
    float* __restrict__ ob = out + (size_t)b * kL * kNm * 2;

    for (int t0 = 0; t0 < kL; t0 += kPF) {
        float ur[kPF], ui[kPF];
        float d0r[kPF], d0i[kPF], d1r[kPF], d1i[kPF];
#pragma unroll
        for (int s = 0; s < kPF; ++s) {
            const int t = t0 + s;
            ur[s]  = ubr[t * kUStep + lane];
            ui[s]  = ubi[t * kUStep + lane];
            d0r[s] = xbr[t * kNm + 0];
            d0i[s] = xbi[t * kNm + 0];
            d1r[s] = xbr[t * kNm + 1];
            d1i[s] = xbi[t * kNm + 1];
        }
#pragma unroll
        for (int s = 0; s < kPF; ++s) {
            const float a = ur[s], c = ui[s];

            // per-lane partial products for v[i] = sum_l w[i,l] * u[l]
            float p0r = w0r * a - w0i * c;
            float p0i = w0r * c + w0i * a;
            float p1r = w1r * a - w1i * c;
            float p1i = w1r * c + w1i * a;
            float pe  = a * a + c * c;

            const float v0r = wsum(p0r);
            const float v0i = wsum(p0i);
            const float v1r = wsum(p1r);
            const float v1i = wsum(p1i);
            const float uen = wsum(pe) + kEps;

            // k = v * f  (pre-update f) -- this is the step output
            const float k0r = v0r * f0r - v0i * f0i;
            const float k0i = v0r * f0i + v0i * f0r;
            const float k1r = v1r * f1r - v1i * f1i;
            const float k1i = v1r * f1i + v1i * f1r;

            if (lane == 0) {
                *reinterpret_cast<float4*>(ob + (size_t)(t0 + s) * 4) =
                    make_float4(k0r, k0i, k1r, k1i);
            }

            // psi = |f|/f = conj(f)/|f| = f^* * rsqrt(|f|^2)
            const float inv_af0 = fast_rsq(f0r * f0r + f0i * f0i);
            const float inv_af1 = fast_rsq(f1r * f1r + f1i * f1i);
            const float ps0r = f0r * inv_af0, ps0i = -f0i * inv_af0;
            const float ps1r = f1r * inv_af1, ps1i = -f1i * inv_af1;

            // e_w = d * psi - v
            const float ew0r = d0r[s] * ps0r - d0i[s] * ps0i - v0r;
            const float ew0i = d0r[s] * ps0i + d0i[s] * ps0r - v0i;
            const float ew1r = d1r[s] * ps1r - d1i[s] * ps1i - v1r;
            const float ew1i = d1r[s] * ps1i + d1i[s] * ps1r - v1i;

            // e_f = d - k
            const float ef0r = d0r[s] - k0r, ef0i = d0i[s] - k0i;
            const float ef1r = d1r[s] - k1r, ef1i = d1i[s] - k1i;

            // gf = -(1/v_energy) * e_f * conj(v)
            const float ven = v0r * v0r + v0i * v0i + v1r * v1r + v1i * v1i + kEps;
            const float nv = -fast_rcp(ven);
            float gf0r = nv * (ef0r * v0r + ef0i * v0i);
            float gf0i = nv * (ef0i * v0r - ef0r * v0i);
            float gf1r = nv * (ef1r * v1r + ef1i * v1i);
            float gf1i = nv * (ef1i * v1r - ef1r * v1i);

            // clip |gf| at GRAD_MAX: scale = min(1, 30 * rsqrt(|gf|^2))
            const float m0 = gf0r * gf0r + gf0i * gf0i;
            const float m1 = gf1r * gf1r + gf1i * gf1i;
            const float sc0 = fminf(1.0f, kGradMax * fast_rsq(m0));
            const float sc1 = fminf(1.0f, kGradMax * fast_rsq(m1));
            gf0r *= sc0; gf0i *= sc0;
            gf1r *= sc1; gf1i *= sc1;

            // f -= lr_f * gf
            f0r -= kLrF * gf0r; f0i -= kLrF * gf0i;
            f1r -= kLrF * gf1r; f1i -= kLrF * gf1i;

            // w += (lr_w / u_energy) * e_w * conj(u)   (per-lane element)
            const float su = kLrW * fast_rcp(uen);
            const float c0r = su * ew0r, c0i = su * ew0i;
            const float c1r = su * ew1r, c1i = su * ew1i;
            w0r += c0r * a + c0i * c;
            w0i += c0i * a - c0r * c;
            w1r += c1r * a + c1i * c;
            w1i += c1i * a - c1r * c;
        }
    }
}

} // namespace

extern "C" void kernel_launch(void* const* d_in, const int* in_sizes, int n_in,
                              void* d_out, int out_size, void* d_ws, size_t ws_size,
                              hipStream_t stream) {
    const float* u_r  = (const float*)d_in[0];
    const float* u_i  = (const float*)d_in[1];
    const float* x_r  = (const float*)d_in[2];
    const float* x_i  = (const float*)d_in[3];
    const float* w0_r = (const float*)d_in[4];
    const float* w0_i = (const float*)d_in[5];
    const float* f0_r = (const float*)d_in[6];
    const float* f0_i = (const float*)d_in[7];
    float* out = (float*)d_out;

    dim3 grid(kB);
    dim3 block(64);
    adf_kernel<<<grid, block, 0, stream>>>(u_r, u_i, x_r, x_i,
                                           w0_r, w0_i, f0_r, f0_i, out);
}

// Round 3
// 1074.511 us; speedup vs baseline: 2.9789x; 1.3358x over previous
//
#include <hip/hip_runtime.h>

namespace {

constexpr int kB = 64;
constexpr int kL = 4096;
constexpr float kLrW = 1.0f / 64.0f;
constexpr float kLrF = 1.0f / 128.0f;
constexpr float kGradMax = 30.0f;
constexpr float kEps = 1e-9f;
constexpr int kPF = 8;                // prefetch depth (steps per chunk)

// One DPP add level (VALU pipe). bound_ctrl=true => out-of-pattern lanes add 0.
#define DPP_ADD_F32(v, ctrl)                                                   \
    v += __int_as_float(__builtin_amdgcn_update_dpp(                           \
        0, __float_as_int(v), (ctrl), 0xF, 0xF, true))

// 32-lane-group sum: after this, lane31 = sum(lanes 0..31), lane63 = sum(32..63).
__device__ __forceinline__ float red5(float v) {
    DPP_ADD_F32(v, 0x111);  // row_shr:1
    DPP_ADD_F32(v, 0x112);  // row_shr:2
    DPP_ADD_F32(v, 0x114);  // row_shr:4
    DPP_ADD_F32(v, 0x118);  // row_shr:8
    DPP_ADD_F32(v, 0x142);  // row_bcast:15
    return v;
}

__device__ __forceinline__ float rl(float v, int lane) {
    return __int_as_float(__builtin_amdgcn_readlane(__float_as_int(v), lane));
}

__device__ __forceinline__ float fast_rcp(float x) { return __builtin_amdgcn_rcpf(x); }
__device__ __forceinline__ float fast_rsq(float x) { return __builtin_amdgcn_rsqf(x); }

__global__ __launch_bounds__(64, 1) void adf_kernel(
    const float* __restrict__ u_r, const float* __restrict__ u_i,
    const float* __restrict__ x_r, const float* __restrict__ x_i,
    const float* __restrict__ w0r_g, const float* __restrict__ w0i_g,
    const float* __restrict__ f0r_g, const float* __restrict__ f0i_g,
    float* __restrict__ out)
{
    const int b = blockIdx.x;
    const int lane = threadIdx.x;     // 0..63
    const int half = lane >> 5;       // output-mode this lane owns
    const int tap  = lane & 31;
    const bool lo  = (half == 0);

    // Lane owns w[half][j=0][tap] (A) and w[half][j=1][tap] (B).
    // w flat layout: ((b*2+i)*2+j)*32+tap = b*128 + i*64 + j*32 + tap
    const int wbase = b * 128 + half * 64 + tap;
    float wAr = w0r_g[wbase],      wAi = w0i_g[wbase];
    float wBr = w0r_g[wbase + 32], wBi = w0i_g[wbase + 32];

    // Per-half f state and hoisted psi = conj(f)/|f| state.
    float fr = f0r_g[b * 2 + half];
    float fi = f0i_g[b * 2 + half];
    {
        const float mf = fr * fr + fi * fi;
        const float invf = fast_rsq(mf);
        // psi stored as state, consumed by e_w next step
        fr = fr; fi = fi;
        // fallthrough below
    }
    float invf0 = fast_rsq(fr * fr + fi * fi);
    float psr = fr * invf0, psm = -fi * invf0;   // psi real, imag

    // u flat: ((b*L+t)*32+tap) float2 covers (tap, j=0..1)
    const float2* __restrict__ ur2 = (const float2*)u_r + (size_t)b * kL * 32;
    const float2* __restrict__ ui2 = (const float2*)u_i + (size_t)b * kL * 32;
    const float2* __restrict__ xr2 = (const float2*)x_r + (size_t)b * kL;
    const float2* __restrict__ xi2 = (const float2*)x_i + (size_t)b * kL;
    float2* __restrict__ ob2 = (float2*)out + (size_t)b * kL * 2;

    for (int t0 = 0; t0 < kL; t0 += kPF) {
        float2 uR[kPF], uI[kPF], dR[kPF], dI[kPF];
        float su[kPF];
#pragma unroll
        for (int s = 0; s < kPF; ++s) {
            uR[s] = ur2[(size_t)(t0 + s) * 32 + tap];
            uI[s] = ui2[(size_t)(t0 + s) * 32 + tap];
            dR[s] = xr2[t0 + s];
            dI[s] = xi2[t0 + s];
        }
        // u_energy and su = lr_w / (sum|u|^2 + eps): state-independent, off the
        // serial chain; 8 independent reduce chains interleave in stall slots.
#pragma unroll
        for (int s = 0; s < kPF; ++s) {
            float e = uR[s].x * uR[s].x;
            e = fmaf(uR[s].y, uR[s].y, e);
            e = fmaf(uI[s].x, uI[s].x, e);
            e = fmaf(uI[s].y, uI[s].y, e);
            e = red5(e);
            su[s] = kLrW * fast_rcp(rl(e, 31) + kEps);
        }
#pragma unroll
        for (int s = 0; s < kPF; ++s) {
            const float2 urr = uR[s], uii = uI[s];

            // own-mode complex dot partial: p = sum_j w[half][j][tap]*u[tap][j]
            float pr = wAr * urr.x;
            pr = fmaf(-wAi, uii.x, pr);
            pr = fmaf(wBr, urr.y, pr);
            pr = fmaf(-wBi, uii.y, pr);
            float pi = wAr * uii.x;
            pi = fmaf(wAi, urr.x, pi);
            pi = fmaf(wBr, uii.y, pi);
            pi = fmaf(wBi, urr.y, pi);

            pr = red5(pr);
            pi = red5(pi);
            const float v0r = rl(pr, 31), v1r = rl(pr, 63);
            const float v0i = rl(pi, 31), v1i = rl(pi, 63);

            // per-lane mode-selected values
            const float vr = lo ? v0r : v1r;
            const float vi = lo ? v0i : v1i;
            const float dr = lo ? dR[s].x : dR[s].y;
            const float di = lo ? dI[s].x : dI[s].y;

            // k = v * f  (pre-update f) -- step output
            const float kr = vr * fr - vi * fi;
            const float ki = vr * fi + vi * fr;
            if (tap == 0) {
                ob2[(size_t)(t0 + s) * 2 + half] = make_float2(kr, ki);
            }

            // e_f = d - k
            const float efr = dr - kr, efi = di - ki;

            // v_energy (uniform, from broadcast values)
            float ven = v0r * v0r;
            ven = fmaf(v0i, v0i, ven);
            ven = fmaf(v1r, v1r, ven);
            ven = fmaf(v1i, v1i, ven);
            ven += kEps;
            const float nv = -fast_rcp(ven);

            // gf = -(1/ven) * e_f * conj(v), clipped to |gf| <= 30
            float gfr = nv * (efr * vr + efi * vi);
            float gfi = nv * (efi * vr - efr * vi);
            const float mg = gfr * gfr + gfi * gfi;
            const float sc = fminf(1.0f, kGradMax * fast_rsq(mg));
            gfr *= sc; gfi *= sc;

            // e_w = d * psi - v  (psi is state from previous step's f)
            const float ewr = dr * psr - di * psm - vr;
            const float ewi = dr * psm + di * psr - vi;

            // f update
            fr = fmaf(-kLrF, gfr, fr);
            fi = fmaf(-kLrF, gfi, fi);

            // psi for next step (off the critical w-cycle: full step of slack)
            const float mf = fr * fr + fi * fi;
            const float invf = fast_rsq(mf);
            psr = fr * invf;
            psm = -fi * invf;

            // w += su * e_w * conj(u)   (c is per-half already)
            const float cr = su[s] * ewr, ci = su[s] * ewi;
            wAr = fmaf(cr, urr.x, fmaf(ci, uii.x, wAr));
            wAi = fmaf(ci, urr.x, fmaf(-cr, uii.x, wAi));
            wBr = fmaf(cr, urr.y, fmaf(ci, uii.y, wBr));
            wBi = fmaf(ci, urr.y, fmaf(-cr, uii.y, wBi));
        }
    }
}

} // namespace

extern "C" void kernel_launch(void* const* d_in, const int* in_sizes, int n_in,
                              void* d_out, int out_size, void* d_ws, size_t ws_size,
                              hipStream_t stream) {
    const float* u_r  = (const float*)d_in[0];
    const float* u_i  = (const float*)d_in[1];
    const float* x_r  = (const float*)d_in[2];
    const float* x_i  = (const float*)d_in[3];
    const float* w0_r = (const float*)d_in[4];
    const float* w0_i = (const float*)d_in[5];
    const float* f0_r = (const float*)d_in[6];
    const float* f0_i = (const float*)d_in[7];
    float* out = (float*)d_out;

    dim3 grid(kB);
    dim3 block(64);
    adf_kernel<<<grid, block, 0, stream>>>(u_r, u_i, x_r, x_i,
                                           w0_r, w0_i, f0_r, f0_i, out);
}